// Round 11
// baseline (661.466 us; speedup 1.0000x reference)
//
#include <hip/hip_runtime.h>
#include <math.h>

#define EPS 1e-5f

typedef __attribute__((ext_vector_type(8))) short bf16x8;
typedef __attribute__((ext_vector_type(4))) float f32x4;
typedef __attribute__((ext_vector_type(4))) short s16x4;

__device__ __forceinline__ float fast_rcp(float x){ return __builtin_amdgcn_rcpf(x); }
__device__ __forceinline__ float sigf(float x){ return fast_rcp(1.0f + __expf(-x)); }
__device__ __forceinline__ float tanhfast(float x){ return fmaf(2.0f, fast_rcp(1.0f + __expf(-2.0f*x)), -1.0f); }
__device__ __forceinline__ short f2bf(float f){
  unsigned u = __float_as_uint(f);
  u = (u + 0x7FFFu + ((u>>16)&1u)) >> 16;
  return (short)u;
}
__device__ __forceinline__ unsigned cvtpk_bf16(float lo, float hi){
  unsigned r; asm("v_cvt_pk_bf16_f32 %0, %1, %2" : "=v"(r) : "v"(lo), "v"(hi)); return r;
}

// ---------------- conv1 + bn1 partial stats ----------------
__global__ __launch_bounds__(256) void k_conv1_stats(
    const float* __restrict__ x, const float* __restrict__ w1,
    const float* __restrict__ b1, float* __restrict__ part)
{
  __shared__ float red[4][32];
  float s[16], q[16];
#pragma unroll
  for (int f=0; f<16; ++f) { s[f]=0.f; q[f]=0.f; }
  float w1r[128];
#pragma unroll
  for (int i=0; i<128; ++i) w1r[i] = w1[i];
  float b1r[16];
#pragma unroll
  for (int f=0; f<16; ++f) b1r[f] = b1[f];
  const int tid = threadIdx.x;
  for (int iter=0; iter<8; ++iter) {
    int n = blockIdx.x*2048 + iter*256 + tid;
    int b = n >> 7, t = n & 127;
    const float* xb = x + b*1024 + t;
    float xv[8];
#pragma unroll
    for (int ch=0; ch<8; ++ch) xv[ch] = xb[ch*128];
#pragma unroll
    for (int f=0; f<16; ++f) {
      float v = b1r[f];
#pragma unroll
      for (int ch=0; ch<8; ++ch) v = fmaf(xv[ch], w1r[f*8+ch], v);
      s[f] += v; q[f] = fmaf(v,v,q[f]);
    }
  }
#pragma unroll
  for (int f=0; f<16; ++f) {
#pragma unroll
    for (int d=32; d>0; d>>=1) { s[f] += __shfl_down(s[f],d); q[f] += __shfl_down(q[f],d); }
  }
  const int lane = tid & 63, wv = tid >> 6;
  if (lane == 0) {
#pragma unroll
    for (int f=0; f<16; ++f) { red[wv][2*f] = s[f]; red[wv][2*f+1] = q[f]; }
  }
  __syncthreads();
  if (tid < 32) {
    float v = red[0][tid] + red[1][tid] + red[2][tid] + red[3][tid];
    part[blockIdx.x*32 + tid] = v;
  }
}

// ---------------- reduce partials + finalize scale/shift ----------------
__global__ __launch_bounds__(256) void k_reduce_finalize(
    const float* __restrict__ part, int nblk, int C,
    const float* __restrict__ g, const float* __restrict__ b,
    float* __restrict__ prm, float invN)
{
  __shared__ float red[4][2];
  const int c = blockIdx.x;
  const int tid = threadIdx.x;
  float s=0.f, q=0.f;
  for (int i=tid; i<nblk; i+=256) {
    s += part[(size_t)i*2*C + 2*c];
    q += part[(size_t)i*2*C + 2*c + 1];
  }
#pragma unroll
  for (int d=32; d>0; d>>=1) { s += __shfl_down(s,d); q += __shfl_down(q,d); }
  const int lane = tid & 63, wv = tid >> 6;
  if (lane==0) { red[wv][0]=s; red[wv][1]=q; }
  __syncthreads();
  if (tid==0) {
    s = red[0][0]+red[1][0]+red[2][0]+red[3][0];
    q = red[0][1]+red[1][1]+red[2][1]+red[3][1];
    float m = s*invN;
    float v = q*invN - m*m;
    float sc = g[c] / sqrtf(v + EPS);
    prm[2*c]   = sc;
    prm[2*c+1] = fmaf(-m, sc, b[c]);
  }
}

// ---------------- conv1(recompute)+bn1+prelu -> conv2 -> raw out + bn2 partials ----------------
__global__ __launch_bounds__(256) void k_conv2(
    const float* __restrict__ x,
    const float* __restrict__ w1, const float* __restrict__ b1,
    const float* __restrict__ prm1, const float* __restrict__ prelu1,
    const float* __restrict__ w2, const float* __restrict__ b2,
    float* __restrict__ sig, float* __restrict__ part2)
{
  __shared__ float xb[1024];
  __shared__ float h1p[16*136];
  __shared__ float w2s[32*16*12];
  __shared__ float w1s[128];
  __shared__ float p1s[32];
  int tid = threadIdx.x; int b = blockIdx.x;
  *(float4*)&xb[tid*4] = *(const float4*)&x[b*1024 + tid*4];
  for (int i=tid; i<5120; i+=256) { int ff=i/10, k=i-ff*10; w2s[ff*12+k] = w2[i]; }
  if (tid<128) w1s[tid] = w1[tid];
  if (tid<32)  p1s[tid] = prm1[tid];
  float a1 = prelu1[0];
  __syncthreads();
#pragma unroll
  for (int r=0; r<8; ++r) {
    int o = tid + 256*r; int f = o>>7, t = o&127;
    float v = b1[f];
#pragma unroll
    for (int ch=0; ch<8; ++ch) v = fmaf(xb[ch*128+t], w1s[f*8+ch], v);
    v = fmaf(v, p1s[2*f], p1s[2*f+1]);
    v = (v>=0.f) ? v : a1*v;
    h1p[f*136 + t] = v;
  }
  __syncthreads();
  int f2 = tid>>3, wb = (tid&7)*8;
  float acc[8];
  float bb = b2[f2];
#pragma unroll
  for (int j=0;j<8;++j) acc[j]=bb;
  for (int f1=0; f1<16; ++f1) {
    const float* hrow = &h1p[f1*136 + 2*wb];
    float hw[24];
#pragma unroll
    for (int m=0;m<6;++m) *(float4*)&hw[m*4] = *(const float4*)&hrow[m*4];
    const float* wr = &w2s[(f2*16+f1)*12];
    float wk[10];
    *(float4*)&wk[0] = *(const float4*)&wr[0];
    *(float4*)&wk[4] = *(const float4*)&wr[4];
    wk[8]=wr[8]; wk[9]=wr[9];
#pragma unroll
    for (int j=0;j<8;++j)
#pragma unroll
      for (int k=0;k<10;++k) acc[j] = fmaf(hw[2*j+k], wk[k], acc[j]);
  }
  float s=0.f, q=0.f;
#pragma unroll
  for (int j=0;j<8;++j) {
    int w = wb+j;
    if (w < 60) { sig[b*1920 + f2*60 + w] = acc[j]; s += acc[j]; q = fmaf(acc[j],acc[j],q); }
  }
  s += __shfl_down(s,4,8); q += __shfl_down(q,4,8);
  s += __shfl_down(s,2,8); q += __shfl_down(q,2,8);
  s += __shfl_down(s,1,8); q += __shfl_down(q,1,8);
  if ((tid&7)==0) {
    part2[(size_t)b*64 + 2*f2]     = s;
    part2[(size_t)b*64 + 2*f2 + 1] = q;
  }
}

// ---------------- cosine table ----------------
__global__ void k_costab(float* __restrict__ ct)
{
  int i = blockIdx.x*256 + threadIdx.x;
  if (i < 3600) {
    int k = i/60, n = i - k*60;
    int m = (k*n) % 60;
    ct[i] = cosf(0.104719755119659775f * (float)m);
  }
}

// ---------------- bn2-apply + prelu (in-place) + cos transform -> fft ----------------
__global__ __launch_bounds__(256) void k_sigfft(
    float* __restrict__ sig, float* __restrict__ fft,
    const float* __restrict__ prm2, const float* __restrict__ prelu2,
    const float* __restrict__ ctab)
{
  __shared__ float ct[3600];
  __shared__ float rowb[4][4][60];
  int tid = threadIdx.x;
  for (int i=tid; i<3600; i+=256) ct[i] = ctab[i];
  int r4 = tid>>6, lane = tid&63;
  float a2 = prelu2[0];
  __syncthreads();
#pragma unroll
  for (int it=0; it<4; ++it) {
    int row = blockIdx.x*16 + it*4 + r4;
    int c = row & 31;
    float sc = prm2[2*c], sh = prm2[2*c+1];
    size_t base = (size_t)row*60;
    if (lane < 60) {
      float v = fmaf(sig[base+lane], sc, sh);
      v = (v>=0.f) ? v : a2*v;
      rowb[it][r4][lane] = v;
      sig[base+lane] = v;
    }
    if (lane < 60) {
      float s = 0.f;
      const float* rb = rowb[it][r4];
#pragma unroll 6
      for (int n=0; n<60; ++n) s = fmaf(rb[n], ct[n*60+lane], s);
      fft[base+lane] = s;
    }
  }
}

// ---------------- sig+fft -> combined bf16 MFMA B-fragment ----------------
// frag[((t*512+sg)*64 + l)*8 + j]:
//   m=l&15, g=l>>4; stream = (m<8 ? sig : fft); sample = 8*sg + (m&7); k = 8g+j
// (direct flat indexing — the LSTM "time" axis is the flat reinterpretation)
__global__ __launch_bounds__(256) void k_xfrag2(
    const float* __restrict__ sig, const float* __restrict__ fft,
    short* __restrict__ frag)
{
  const int tid = threadIdx.x;
  const int wv = tid >> 6, l = tid & 63;
  const int id = blockIdx.x*4 + wv;          // t*512 + sg
  const int t = id >> 9, sg = id & 511;
  const int m = l & 15, g = l >> 4;
  const float* src = (m < 8) ? sig : fft;
  const float* p = src + (size_t)t*131072 + (size_t)(8*sg + (m&7))*32 + 8*g;
  float4 v0 = *(const float4*)p;
  float4 v1 = *(const float4*)(p+4);
  bf16x8 v;
  v[0]=f2bf(v0.x); v[1]=f2bf(v0.y); v[2]=f2bf(v0.z); v[3]=f2bf(v0.w);
  v[4]=f2bf(v1.x); v[5]=f2bf(v1.y); v[6]=f2bf(v1.z); v[7]=f2bf(v1.w);
  *(bf16x8*)(frag + ((size_t)id*64 + l)*8) = v;
}

// ---------------- barrier-free MFMA LSTM: wave = 8 samples x {sig,fft} ----------------
// phase-split: gates h2=0 computed between the two MFMA phases for overlap
__global__ __launch_bounds__(64,2) void k_lstm8(
    const short* __restrict__ fragA, const short* __restrict__ fragB,
    float* __restrict__ routA, float* __restrict__ routB,
    const float* __restrict__ wihf, const float* __restrict__ whhf,
    const float* __restrict__ bihf, const float* __restrict__ bhhf,
    const float* __restrict__ wihr, const float* __restrict__ whhr,
    const float* __restrict__ bihr, const float* __restrict__ bhhr)
{
  __shared__ short hb[640];                  // [col m][u] stride 40 halves
  const int l = threadIdx.x & 63;
  const int m = l & 15, g = l >> 4;
  const int sg = blockIdx.x;                 // 0..511
  const int dir = blockIdx.y;
  const int br = blockIdx.z;
  const short* frag = br ? fragB : fragA;
  float* out = br ? routB : routA;
  const float* wih = dir ? wihr : wihf;
  const float* whh = dir ? whhr : whhf;
  const float* bih = dir ? bihr : bihf;
  const float* bhh = dir ? bhhr : bhhf;

  bf16x8 Ax[8], Ah[8];
#pragma unroll
  for (int rt=0; rt<8; ++rt) {
    const float* wr = wih + (size_t)(16*rt+m)*32 + 8*g;
    const float* hr = whh + (size_t)(16*rt+m)*32 + 8*g;
#pragma unroll
    for (int j=0;j<8;++j){ Ax[rt][j]=f2bf(wr[j]); Ah[rt][j]=f2bf(hr[j]); }
  }
  f32x4 bias[8];
#pragma unroll
  for (int rt=0; rt<8; ++rt)
#pragma unroll
    for (int r=0;r<4;++r){ int R=16*rt+4*g+r; bias[rt][r]=bih[R]+bhh[R]; }

  for (int i=l; i<320; i+=64) ((int*)hb)[i] = 0;

  float cst[2][4];
#pragma unroll
  for (int h2=0;h2<2;++h2)
#pragma unroll
    for (int r=0;r<4;++r) cst[h2][r]=0.f;

  const int tt0 = dir ? 59 : 0;
  bf16x8 bx = *(const bf16x8*)(frag + ((size_t)(tt0*512+sg)*64 + l)*8);
  float* outb = out + (size_t)(8*sg+m)*64 + dir*32 + 4*g;  // used only when m<8

  for (int q=0; q<60; ++q) {
    const int tt = dir ? (59-q) : q;
    bf16x8 bh = *(const bf16x8*)(hb + m*40 + 8*g);
    bf16x8 bxn;
    if (q < 59) {
      const int tn = dir ? (58-q) : (q+1);
      bxn = *(const bf16x8*)(frag + ((size_t)(tn*512+sg)*64 + l)*8);
    }
    f32x4 acc[8];
    // phase A: tiles feeding h2=0 gates (rt = 0,2,4,6)
#pragma unroll
    for (int G=0; G<4; ++G) {
      int rt = 2*G;
      acc[rt] = __builtin_amdgcn_mfma_f32_16x16x32_bf16(Ax[rt], bx, bias[rt], 0,0,0);
      acc[rt] = __builtin_amdgcn_mfma_f32_16x16x32_bf16(Ah[rt], bh, acc[rt], 0,0,0);
    }
    // gates h2=0 — overlaps phase-B MFMA issue
    {
      float hnf[4];
#pragma unroll
      for (int r=0; r<4; ++r) {
        float gi = acc[0][r], gf = acc[2][r];
        float gg = acc[4][r], go = acc[6][r];
        float cn = sigf(gf)*cst[0][r] + sigf(gi)*tanhfast(gg);
        cst[0][r] = cn;
        hnf[r] = sigf(go)*tanhfast(cn);
      }
      uint2 hv; hv.x = cvtpk_bf16(hnf[0],hnf[1]); hv.y = cvtpk_bf16(hnf[2],hnf[3]);
      *(uint2*)(hb + m*40 + 4*g) = hv;
      float4 o;
      o.x = hnf[0] + __shfl_xor(hnf[0], 8);
      o.y = hnf[1] + __shfl_xor(hnf[1], 8);
      o.z = hnf[2] + __shfl_xor(hnf[2], 8);
      o.w = hnf[3] + __shfl_xor(hnf[3], 8);
      if (m < 8) *(float4*)(outb + (size_t)tt*262144) = o;
    }
    // phase B: tiles feeding h2=1 gates (rt = 1,3,5,7)
#pragma unroll
    for (int G=0; G<4; ++G) {
      int rt = 2*G+1;
      acc[rt] = __builtin_amdgcn_mfma_f32_16x16x32_bf16(Ax[rt], bx, bias[rt], 0,0,0);
      acc[rt] = __builtin_amdgcn_mfma_f32_16x16x32_bf16(Ah[rt], bh, acc[rt], 0,0,0);
    }
    {
      float hnf[4];
#pragma unroll
      for (int r=0; r<4; ++r) {
        float gi = acc[1][r], gf = acc[3][r];
        float gg = acc[5][r], go = acc[7][r];
        float cn = sigf(gf)*cst[1][r] + sigf(gi)*tanhfast(gg);
        cst[1][r] = cn;
        hnf[r] = sigf(go)*tanhfast(cn);
      }
      uint2 hv; hv.x = cvtpk_bf16(hnf[0],hnf[1]); hv.y = cvtpk_bf16(hnf[2],hnf[3]);
      *(uint2*)(hb + m*40 + 16 + 4*g) = hv;
      float4 o;
      o.x = hnf[0] + __shfl_xor(hnf[0], 8);
      o.y = hnf[1] + __shfl_xor(hnf[1], 8);
      o.z = hnf[2] + __shfl_xor(hnf[2], 8);
      o.w = hnf[3] + __shfl_xor(hnf[3], 8);
      if (m < 8) *(float4*)(outb + (size_t)tt*262144 + 16) = o;
    }
    bx = bxn;
  }
}

// ---------------- bnf stats ----------------
__global__ __launch_bounds__(256) void k_bnfstats(const float* __restrict__ rb, float* __restrict__ acc)
{
  int col = blockIdx.x*256 + threadIdx.x;
  size_t r0 = (size_t)blockIdx.y*256;
  const float* p = rb + r0*3840 + col;
  float s=0.f, q=0.f;
  for (int r=0; r<256; ++r) { float v = p[(size_t)r*3840]; s += v; q = fmaf(v,v,q); }
  atomicAdd(&acc[2*col], s); atomicAdd(&acc[2*col+1], q);
}

// ---------------- finalize ----------------
__global__ void k_finalize_bn(const float* __restrict__ acc, const float* __restrict__ g,
                              const float* __restrict__ b, float* __restrict__ prm,
                              int C, float invN)
{
  int i = blockIdx.x*blockDim.x + threadIdx.x;
  if (i < C) {
    float m = acc[2*i]*invN;
    float v = acc[2*i+1]*invN - m*m;
    float sc = g[i] / sqrtf(v + EPS);
    prm[2*i]   = sc;
    prm[2*i+1] = fmaf(-m, sc, b[i]);
  }
}

// ---------------- bn1d-apply + correlation + final conv ----------------
__global__ __launch_bounds__(64) void k_corr(
    const float* __restrict__ ra, const float* __restrict__ rb,
    const float* __restrict__ pfa, const float* __restrict__ pfb,
    const float* __restrict__ cw, const float* __restrict__ cb,
    float* __restrict__ dout)
{
  __shared__ float sxt[12], sxx[12], stt[12], cv[12];
  int lane = threadIdx.x; int r = blockIdx.x;
  if (lane < 12) { sxt[lane]=0.f; sxx[lane]=0.f; stt[lane]=0.f; }
  __syncthreads();
  const float* pa = ra + (size_t)r*3840;
  const float* pb = rb + (size_t)r*3840;
  float xt0=0,xx0=0,tt0=0, xt1=0,xx1=0,tt1=0, xt2=0,xx2=0,tt2=0;
  for (int i=0; i<60; i+=3) {
    { int fe = lane + 64*i;
      float a = fmaf(pa[fe], pfa[2*fe], pfa[2*fe+1]);
      float b = fmaf(pb[fe], pfb[2*fe], pfb[2*fe+1]);
      xt0 = fmaf(a,b,xt0); xx0 = fmaf(a,a,xx0); tt0 = fmaf(b,b,tt0); }
    { int fe = lane + 64*(i+1);
      float a = fmaf(pa[fe], pfa[2*fe], pfa[2*fe+1]);
      float b = fmaf(pb[fe], pfb[2*fe], pfb[2*fe+1]);
      xt1 = fmaf(a,b,xt1); xx1 = fmaf(a,a,xx1); tt1 = fmaf(b,b,tt1); }
    { int fe = lane + 64*(i+2);
      float a = fmaf(pa[fe], pfa[2*fe], pfa[2*fe+1]);
      float b = fmaf(pb[fe], pfb[2*fe], pfb[2*fe+1]);
      xt2 = fmaf(a,b,xt2); xx2 = fmaf(a,a,xx2); tt2 = fmaf(b,b,tt2); }
  }
  int c0 = lane % 12;
  int c1 = (c0+4) % 12;
  int c2 = (c0+8) % 12;
  atomicAdd(&sxt[c0], xt0); atomicAdd(&sxx[c0], xx0); atomicAdd(&stt[c0], tt0);
  atomicAdd(&sxt[c1], xt1); atomicAdd(&sxx[c1], xx1); atomicAdd(&stt[c1], tt1);
  atomicAdd(&sxt[c2], xt2); atomicAdd(&sxx[c2], xx2); atomicAdd(&stt[c2], tt2);
  __syncthreads();
  if (lane < 12) {
    float corr = sxt[lane] / sqrtf(stt[lane]) / sqrtf(sxx[lane]);
    cv[lane] = corr;
    dout[49152 + r*12 + lane] = corr;
  }
  __syncthreads();
  if (lane < 12) {
    float o = cb[0];
#pragma unroll
    for (int k=0; k<5; ++k) { int j = lane + k - 2; if (j>=0 && j<12) o = fmaf(cv[j], cw[k], o); }
    dout[r*12 + lane] = o;
  }
}

// ---------------- host ----------------
extern "C" void kernel_launch(void* const* d_in, const int* in_sizes, int n_in,
                              void* d_out, int out_size, void* d_ws, size_t ws_size,
                              hipStream_t stream)
{
  const float* x    = (const float*)d_in[0];
  const float* tpl  = (const float*)d_in[1];
  const float* w1   = (const float*)d_in[2];
  const float* b1   = (const float*)d_in[3];
  const float* g1   = (const float*)d_in[4];
  const float* bb1  = (const float*)d_in[5];
  const float* p1   = (const float*)d_in[6];
  const float* w2   = (const float*)d_in[7];
  const float* b2   = (const float*)d_in[8];
  const float* g2   = (const float*)d_in[9];
  const float* bb2  = (const float*)d_in[10];
  const float* p2   = (const float*)d_in[11];
  const float* wihf = (const float*)d_in[12];
  const float* whhf = (const float*)d_in[13];
  const float* bihf = (const float*)d_in[14];
  const float* bhhf = (const float*)d_in[15];
  const float* wihr = (const float*)d_in[16];
  const float* whhr = (const float*)d_in[17];
  const float* bihr = (const float*)d_in[18];
  const float* bhhr = (const float*)d_in[19];
  const float* gf   = (const float*)d_in[20];
  const float* bf   = (const float*)d_in[21];
  const float* cw   = (const float*)d_in[22];
  const float* cb   = (const float*)d_in[23];
  float* W   = (float*)d_ws;
  float* out = (float*)d_out;

  constexpr size_t PRM1A=64, PRM1B=96, PRM2A=256, PRM2B=320;
  constexpr size_t ACCFA=512, ACCFB=8192, PRMFA=15872, PRMFB=23552, CTAB=31232;
  constexpr size_t P1P=35072, P2P=43264;
  constexpr size_t SIGSZ = 7864320, RSZ = 15728640, FRAGF = 7864320;
  constexpr size_t BIG0 = 307200;
  // fast: sigA|fftA|sigB|fftB|rbufA|rbufB|fragA|fragB
  constexpr size_t F_SIGA=BIG0, F_FFTA=F_SIGA+SIGSZ, F_SIGB=F_FFTA+SIGSZ, F_FFTB=F_SIGB+SIGSZ;
  constexpr size_t F_RBUFA=F_FFTB+SIGSZ, F_RBUFB=F_RBUFA+RSZ;
  constexpr size_t F_FR0=F_RBUFB+RSZ;
  constexpr size_t F_TOTAL=(F_FR0 + 2*FRAGF)*sizeof(float);
  // slow: sig|fft|rbufA|rbufB|frag
  constexpr size_t T_SIG=BIG0, T_FFT=T_SIG+SIGSZ, T_RBUFA=T_FFT+SIGSZ, T_RBUFB=T_RBUFA+RSZ;
  constexpr size_t T_FR0=T_RBUFB+RSZ;

  const bool fast = ws_size >= F_TOTAL;

  hipMemsetAsync(W, 0, 262144, stream);
  k_costab<<<15,256,0,stream>>>(W+CTAB);

  if (fast) {
    for (int br=0; br<2; ++br) {
      const float* xin  = br ? tpl : x;
      float* prm1 = W + (br ? PRM1B : PRM1A);
      float* prm2 = W + (br ? PRM2B : PRM2A);
      float* sig  = W + (br ? F_SIGB : F_SIGA);
      float* fft  = W + (br ? F_FFTB : F_FFTA);
      k_conv1_stats<<<256,256,0,stream>>>(xin, w1, b1, W+P1P);
      k_reduce_finalize<<<16,256,0,stream>>>(W+P1P, 256, 16, g1, bb1, prm1, 1.f/524288.f);
      k_conv2<<<4096,256,0,stream>>>(xin, w1, b1, prm1, p1, w2, b2, sig, W+P2P);
      k_reduce_finalize<<<32,256,0,stream>>>(W+P2P, 4096, 32, g2, bb2, prm2, 1.f/245760.f);
      k_sigfft<<<8192,256,0,stream>>>(sig, fft, prm2, p2, W+CTAB);
    }
    short* frA = (short*)(W + F_FR0);
    short* frB = (short*)(W + F_FR0 + FRAGF);
    k_xfrag2<<<7680,256,0,stream>>>(W+F_SIGA, W+F_FFTA, frA);
    k_xfrag2<<<7680,256,0,stream>>>(W+F_SIGB, W+F_FFTB, frB);
    k_lstm8<<<dim3(512,2,2),64,0,stream>>>(frA, frB, W+F_RBUFA, W+F_RBUFB,
        wihf,whhf,bihf,bhhf, wihr,whhr,bihr,bhhr);
    k_bnfstats<<<dim3(15,16),256,0,stream>>>(W+F_RBUFA, W+ACCFA);
    k_bnfstats<<<dim3(15,16),256,0,stream>>>(W+F_RBUFB, W+ACCFB);
    k_finalize_bn<<<15,256,0,stream>>>(W+ACCFA, gf, bf, W+PRMFA, 3840, 1.f/4096.f);
    k_finalize_bn<<<15,256,0,stream>>>(W+ACCFB, gf, bf, W+PRMFB, 3840, 1.f/4096.f);
    k_corr<<<4096,64,0,stream>>>(W+F_RBUFA, W+F_RBUFB, W+PRMFA, W+PRMFB, cw, cb, out);
  } else {
    short* fr = (short*)(W + T_FR0);
    for (int br=0; br<2; ++br) {
      const float* xin  = br ? tpl : x;
      float* prm1 = W + (br ? PRM1B : PRM1A);
      float* prm2 = W + (br ? PRM2B : PRM2A);
      float* sig  = W + T_SIG;
      float* fft  = W + T_FFT;
      float* rbuf = W + (br ? T_RBUFB : T_RBUFA);
      k_conv1_stats<<<256,256,0,stream>>>(xin, w1, b1, W+P1P);
      k_reduce_finalize<<<16,256,0,stream>>>(W+P1P, 256, 16, g1, bb1, prm1, 1.f/524288.f);
      k_conv2<<<4096,256,0,stream>>>(xin, w1, b1, prm1, p1, w2, b2, sig, W+P2P);
      k_reduce_finalize<<<32,256,0,stream>>>(W+P2P, 4096, 32, g2, bb2, prm2, 1.f/245760.f);
      k_sigfft<<<8192,256,0,stream>>>(sig, fft, prm2, p2, W+CTAB);
      k_xfrag2<<<7680,256,0,stream>>>(sig, fft, fr);
      k_lstm8<<<dim3(512,2,1),64,0,stream>>>(fr, fr, rbuf, rbuf,
          wihf,whhf,bihf,bhhf, wihr,whhr,bihr,bhhr);
    }
    k_bnfstats<<<dim3(15,16),256,0,stream>>>(W+T_RBUFA, W+ACCFA);
    k_bnfstats<<<dim3(15,16),256,0,stream>>>(W+T_RBUFB, W+ACCFB);
    k_finalize_bn<<<15,256,0,stream>>>(W+ACCFA, gf, bf, W+PRMFA, 3840, 1.f/4096.f);
    k_finalize_bn<<<15,256,0,stream>>>(W+ACCFB, gf, bf, W+PRMFB, 3840, 1.f/4096.f);
    k_corr<<<4096,64,0,stream>>>(W+T_RBUFA, W+T_RBUFB, W+PRMFA, W+PRMFB, cw, cb, out);
  }
}